// Round 6
// baseline (91.467 us; speedup 1.0000x reference)
//
#include <hip/hip_runtime.h>
#include <hip/hip_fp16.h>
#include <math.h>

#define B_ 16
#define C_ 4
#define M_ 2048

typedef short bf16x8 __attribute__((ext_vector_type(8)));
typedef float f32x4 __attribute__((ext_vector_type(4)));

__device__ inline unsigned short f2bf(float f) {
  union { float f; unsigned u; } v; v.f = f;
  unsigned r = v.u + 0x7fffu + ((v.u >> 16) & 1u);
  return (unsigned short)(r >> 16);
}

__device__ inline bf16x8 pack_bf8(float4 a, float4 b) {
  union { bf16x8 v; unsigned short h[8]; } u;
  u.h[0] = f2bf(a.x); u.h[1] = f2bf(a.y); u.h[2] = f2bf(a.z); u.h[3] = f2bf(a.w);
  u.h[4] = f2bf(b.x); u.h[5] = f2bf(b.y); u.h[6] = f2bf(b.z); u.h[7] = f2bf(b.w);
  return u.v;
}

// Fused single kernel. Block = (frame b, 128-m tile), 512 threads = 8 waves,
// wave = mhalf*4 + c. MFMA core + Ex twiddle-gen + C/D->LDS mapping are the
// R4-verified code. B' fragments built straight from global fp32 (element-
// exact vs the R4 prep table). R6 change: __syncthreads() restored around the
// PS write->read (R5's barrier-less wave-synchronous LDS was the one
// unverified delta vs green R4).
__global__ __launch_bounds__(512, 2) void nufft_gemm(const float* __restrict__ xr,
                                                     const float* __restrict__ xi,
                                                     const float* __restrict__ traj,
                                                     float* __restrict__ out) {
  const int b = blockIdx.x >> 4;
  const int m0 = (blockIdx.x & 15) * 128;
  const int tid = threadIdx.x;
  const int lane = tid & 63;
  const int wave = tid >> 6;
  const int c = wave & 3;
  const int mhalf = wave >> 2;
  const int col = lane & 15;
  const int quad = lane >> 4;

  __shared__ __align__(16) unsigned short ExS[128][136];  // [m][k] bf16 twiddles
  __shared__ float PS[8][16][130];                        // per-wave P' tiles

  // ---- Ex twiddle generation into LDS (R4-verified block).
  {
    const int mh = tid >> 2;         // 0..127
    const int j0 = (tid & 3) * 16;   // 16-step segment
    const int mg = m0 + mh;
    const float kx = traj[((size_t)b * M_ + mg) * 2 + 1];
    float sa, ca, su, cu;
    // Ex[m][j] = exp(-i*kx*(j-32)); re at k=j, im at k=64+j
    sincosf(kx * (float)(j0 - 32), &sa, &ca);
    float vr = ca, vi = -sa;
    sincosf(kx, &su, &cu);
    const float ur = cu, ui = -su;
#pragma unroll
    for (int t = 0; t < 16; ++t) {
      ExS[mh][j0 + t] = f2bf(vr);
      ExS[mh][64 + j0 + t] = f2bf(vi);
      const float nvr = fmaf(vr, ur, -(vi * ui));
      const float nvi = fmaf(vr, ui, vi * ur);
      vr = nvr; vi = nvi;
    }
  }

  // ---- B' fragments straight from global (value table == verified R4 prep):
  //   n = nt*16+col (within c-slice), i = n>>1, ri = n&1 = col&1.
  //   k = ks*32 + quad*8 + jj;  ks<2 -> j=k:      ri? xi[j] :  xr[j]
  //                             ks>=2 -> j=k-64:  ri? xr[j] : -xi[j]
  bf16x8 bfrag[8][4];
  {
    const int ri = col & 1;
#pragma unroll
    for (int nt = 0; nt < 8; ++nt) {
      const int i = (nt * 16 + col) >> 1;
      const float* rowr = xr + (size_t)((b * 4 + c) * 64 + i) * 64;
      const float* rowi = xi + (size_t)((b * 4 + c) * 64 + i) * 64;
#pragma unroll
      for (int ks = 0; ks < 4; ++ks) {
        const int j8 = (ks & 1) * 32 + quad * 8;
        const float* src = (ks < 2) ? (ri ? rowi : rowr) : (ri ? rowr : rowi);
        float4 v0 = *(const float4*)(src + j8);
        float4 v1 = *(const float4*)(src + j8 + 4);
        if (ks >= 2 && !ri) {
          v0 = make_float4(-v0.x, -v0.y, -v0.z, -v0.w);
          v1 = make_float4(-v1.x, -v1.y, -v1.z, -v1.w);
        }
        bfrag[nt][ks] = pack_bf8(v0, v1);
      }
    }
  }
  __syncthreads();  // Ex twiddles ready

  for (int s = 0; s < 4; ++s) {
    const int mt = mhalf * 4 + s;

    // A fragments from LDS (verified pattern)
    bf16x8 af[4];
#pragma unroll
    for (int ks = 0; ks < 4; ++ks)
      af[ks] = *(const bf16x8*)(&ExS[mt * 16 + col][ks * 32 + quad * 8]);

    f32x4 acc[8];
#pragma unroll
    for (int nt = 0; nt < 8; ++nt) acc[nt] = (f32x4){0.f, 0.f, 0.f, 0.f};

#pragma unroll
    for (int ks = 0; ks < 4; ++ks)
#pragma unroll
      for (int nt = 0; nt < 8; ++nt)
        acc[nt] = __builtin_amdgcn_mfma_f32_16x16x32_bf16(af[ks], bfrag[nt][ks], acc[nt], 0, 0, 0);

    __syncthreads();  // A: previous iteration finished reading PS

    // P' -> LDS tile with the verified C/D mapping
#pragma unroll
    for (int nt = 0; nt < 8; ++nt)
#pragma unroll
      for (int r = 0; r < 4; ++r)
        PS[wave][quad * 4 + r][nt * 16 + col] = acc[nt][r];

    __syncthreads();  // B: PS ready

    // ---- Epilogue: lane = rowT*4 + q; row m = mt*16 + rowT.
    // Lane handles i = q, q+4, ..., q+60 (stride 4 -> conflict-free PS reads).
    // Ey[m][i] = exp(-i*ky*(i-32)) via register recurrence, step exp(-i*4ky).
    {
      const int rowT = lane >> 2;
      const int q = lane & 3;
      const int mg = m0 + mt * 16 + rowT;
      const float ky = traj[((size_t)b * M_ + mg) * 2 + 0];
      float sa, ca, s4, c4;
      sincosf(ky * (float)(q - 32), &sa, &ca);
      float wr = ca, wi = -sa;
      sincosf(4.0f * ky, &s4, &c4);
      const float pr = c4, pi = -s4;
      float yr = 0.f, yi = 0.f;
#pragma unroll
      for (int t = 0; t < 16; ++t) {
        const int ii = q + 4 * t;
        const float Pr = PS[wave][rowT][2 * ii + 0];
        const float Pi = PS[wave][rowT][2 * ii + 1];
        yr = fmaf(wr, Pr, fmaf(-wi, Pi, yr));
        yi = fmaf(wr, Pi, fmaf(wi, Pr, yi));
        const float nwr = fmaf(wr, pr, -(wi * pi));
        const float nwi = fmaf(wr, pi, wi * pr);
        wr = nwr; wi = nwi;
      }
      // reduce the 4 quarters
      yr += __shfl_xor(yr, 1, 4); yr += __shfl_xor(yr, 2, 4);
      yi += __shfl_xor(yi, 1, 4); yi += __shfl_xor(yi, 2, 4);
      if (q == 0) {
        float* o = out + ((size_t)(b * 4 + c) * M_ + mg) * 2;
        o[0] = yr;
        o[1] = yi;
      }
    }
  }
}

extern "C" void kernel_launch(void* const* d_in, const int* in_sizes, int n_in,
                              void* d_out, int out_size, void* d_ws, size_t ws_size,
                              hipStream_t stream) {
  const float* xr = (const float*)d_in[0];
  const float* xi = (const float*)d_in[1];
  const float* traj = (const float*)d_in[2];
  float* out = (float*)d_out;
  (void)d_ws; (void)ws_size;

  nufft_gemm<<<B_ * 16, 512, 0, stream>>>(xr, xi, traj, out);
}

// Round 9
// 90.432 us; speedup vs baseline: 1.0115x; 1.0115x over previous
//
#include <hip/hip_runtime.h>
#include <hip/hip_fp16.h>
#include <math.h>

#define B_ 16
#define C_ 4
#define M_ 2048

typedef short bf16x8 __attribute__((ext_vector_type(8)));
typedef float f32x4 __attribute__((ext_vector_type(4)));

__device__ inline unsigned short f2bf(float f) {
  union { float f; unsigned u; } v; v.f = f;
  unsigned r = v.u + 0x7fffu + ((v.u >> 16) & 1u);
  return (unsigned short)(r >> 16);
}

__device__ inline bf16x8 pack_bf8(float4 a, float4 b) {
  union { bf16x8 v; unsigned short h[8]; } u;
  u.h[0] = f2bf(a.x); u.h[1] = f2bf(a.y); u.h[2] = f2bf(a.z); u.h[3] = f2bf(a.w);
  u.h[4] = f2bf(b.x); u.h[5] = f2bf(b.y); u.h[6] = f2bf(b.z); u.h[7] = f2bf(b.w);
  return u.v;
}

// R9 = byte-identical green R6 with ONE token changed:
// __launch_bounds__(512,2) -> (512,1). R6's (512,2) capped VGPRs at 128 and
// spilled bfrag to scratch (22 MB WRITE_SIZE, 48 us). (512,1) lifts the cap
// to 512 -> no spill. Single-variable bisection: if red, the no-spill
// register path itself is the corruption source common to R5/R7/R8.
__global__ __launch_bounds__(512, 1) void nufft_gemm(const float* __restrict__ xr,
                                                     const float* __restrict__ xi,
                                                     const float* __restrict__ traj,
                                                     float* __restrict__ out) {
  const int b = blockIdx.x >> 4;
  const int m0 = (blockIdx.x & 15) * 128;
  const int tid = threadIdx.x;
  const int lane = tid & 63;
  const int wave = tid >> 6;
  const int c = wave & 3;
  const int mhalf = wave >> 2;
  const int col = lane & 15;
  const int quad = lane >> 4;

  __shared__ __align__(16) unsigned short ExS[128][136];  // [m][k] bf16 twiddles
  __shared__ float PS[8][16][130];                        // per-wave P' tiles

  // ---- Ex twiddle generation into LDS (R4-verified block).
  {
    const int mh = tid >> 2;         // 0..127
    const int j0 = (tid & 3) * 16;   // 16-step segment
    const int mg = m0 + mh;
    const float kx = traj[((size_t)b * M_ + mg) * 2 + 1];
    float sa, ca, su, cu;
    // Ex[m][j] = exp(-i*kx*(j-32)); re at k=j, im at k=64+j
    sincosf(kx * (float)(j0 - 32), &sa, &ca);
    float vr = ca, vi = -sa;
    sincosf(kx, &su, &cu);
    const float ur = cu, ui = -su;
#pragma unroll
    for (int t = 0; t < 16; ++t) {
      ExS[mh][j0 + t] = f2bf(vr);
      ExS[mh][64 + j0 + t] = f2bf(vi);
      const float nvr = fmaf(vr, ur, -(vi * ui));
      const float nvi = fmaf(vr, ui, vi * ur);
      vr = nvr; vi = nvi;
    }
  }

  // ---- B' fragments straight from global (value table == verified R4 prep):
  //   n = nt*16+col (within c-slice), i = n>>1, ri = n&1 = col&1.
  //   k = ks*32 + quad*8 + jj;  ks<2 -> j=k:      ri? xi[j] :  xr[j]
  //                             ks>=2 -> j=k-64:  ri? xr[j] : -xi[j]
  bf16x8 bfrag[8][4];
  {
    const int ri = col & 1;
#pragma unroll
    for (int nt = 0; nt < 8; ++nt) {
      const int i = (nt * 16 + col) >> 1;
      const float* rowr = xr + (size_t)((b * 4 + c) * 64 + i) * 64;
      const float* rowi = xi + (size_t)((b * 4 + c) * 64 + i) * 64;
#pragma unroll
      for (int ks = 0; ks < 4; ++ks) {
        const int j8 = (ks & 1) * 32 + quad * 8;
        const float* src = (ks < 2) ? (ri ? rowi : rowr) : (ri ? rowr : rowi);
        float4 v0 = *(const float4*)(src + j8);
        float4 v1 = *(const float4*)(src + j8 + 4);
        if (ks >= 2 && !ri) {
          v0 = make_float4(-v0.x, -v0.y, -v0.z, -v0.w);
          v1 = make_float4(-v1.x, -v1.y, -v1.z, -v1.w);
        }
        bfrag[nt][ks] = pack_bf8(v0, v1);
      }
    }
  }
  __syncthreads();  // Ex twiddles ready

  for (int s = 0; s < 4; ++s) {
    const int mt = mhalf * 4 + s;

    // A fragments from LDS (verified pattern)
    bf16x8 af[4];
#pragma unroll
    for (int ks = 0; ks < 4; ++ks)
      af[ks] = *(const bf16x8*)(&ExS[mt * 16 + col][ks * 32 + quad * 8]);

    f32x4 acc[8];
#pragma unroll
    for (int nt = 0; nt < 8; ++nt) acc[nt] = (f32x4){0.f, 0.f, 0.f, 0.f};

#pragma unroll
    for (int ks = 0; ks < 4; ++ks)
#pragma unroll
      for (int nt = 0; nt < 8; ++nt)
        acc[nt] = __builtin_amdgcn_mfma_f32_16x16x32_bf16(af[ks], bfrag[nt][ks], acc[nt], 0, 0, 0);

    __syncthreads();  // A: previous iteration finished reading PS

    // P' -> LDS tile with the verified C/D mapping
#pragma unroll
    for (int nt = 0; nt < 8; ++nt)
#pragma unroll
      for (int r = 0; r < 4; ++r)
        PS[wave][quad * 4 + r][nt * 16 + col] = acc[nt][r];

    __syncthreads();  // B: PS ready

    // ---- Epilogue: lane = rowT*4 + q; row m = mt*16 + rowT.
    // Lane handles i = q, q+4, ..., q+60 (stride 4 -> conflict-free PS reads).
    // Ey[m][i] = exp(-i*ky*(i-32)) via register recurrence, step exp(-i*4ky).
    {
      const int rowT = lane >> 2;
      const int q = lane & 3;
      const int mg = m0 + mt * 16 + rowT;
      const float ky = traj[((size_t)b * M_ + mg) * 2 + 0];
      float sa, ca, s4, c4;
      sincosf(ky * (float)(q - 32), &sa, &ca);
      float wr = ca, wi = -sa;
      sincosf(4.0f * ky, &s4, &c4);
      const float pr = c4, pi = -s4;
      float yr = 0.f, yi = 0.f;
#pragma unroll
      for (int t = 0; t < 16; ++t) {
        const int ii = q + 4 * t;
        const float Pr = PS[wave][rowT][2 * ii + 0];
        const float Pi = PS[wave][rowT][2 * ii + 1];
        yr = fmaf(wr, Pr, fmaf(-wi, Pi, yr));
        yi = fmaf(wr, Pi, fmaf(wi, Pr, yi));
        const float nwr = fmaf(wr, pr, -(wi * pi));
        const float nwi = fmaf(wr, pi, wi * pr);
        wr = nwr; wi = nwi;
      }
      // reduce the 4 quarters
      yr += __shfl_xor(yr, 1, 4); yr += __shfl_xor(yr, 2, 4);
      yi += __shfl_xor(yi, 1, 4); yi += __shfl_xor(yi, 2, 4);
      if (q == 0) {
        float* o = out + ((size_t)(b * 4 + c) * M_ + mg) * 2;
        o[0] = yr;
        o[1] = yi;
      }
    }
  }
}

extern "C" void kernel_launch(void* const* d_in, const int* in_sizes, int n_in,
                              void* d_out, int out_size, void* d_ws, size_t ws_size,
                              hipStream_t stream) {
  const float* xr = (const float*)d_in[0];
  const float* xi = (const float*)d_in[1];
  const float* traj = (const float*)d_in[2];
  float* out = (float*)d_out;
  (void)d_ws; (void)ws_size;

  nufft_gemm<<<B_ * 16, 512, 0, stream>>>(xr, xi, traj, out);
}